// Round 8
// baseline (117.040 us; speedup 1.0000x reference)
//
#include <hip/hip_runtime.h>

typedef __attribute__((ext_vector_type(4))) float f32x4;
typedef __attribute__((ext_vector_type(8))) short short8;

#define EPSF 1e-12f

__device__ __forceinline__ ushort bf16rne(float x) {
  uint u = __float_as_uint(x);
  u += 0x7fffu + ((u >> 16) & 1u);
  return (ushort)(u >> 16);
}
__device__ __forceinline__ float bf2f(ushort h) {
  return __uint_as_float(((uint)h) << 16);
}
// 8 floats -> hi/lo bf16 short8 pair (pure C: RNE hi, RNE residual lo)
__device__ __forceinline__ void cvt8hl(float4 v0, float4 v1, short8& h8, short8& l8) {
  float vals[8] = {v0.x, v0.y, v0.z, v0.w, v1.x, v1.y, v1.z, v1.w};
#pragma unroll
  for (int j = 0; j < 8; ++j) {
    ushort h = bf16rne(vals[j]);
    h8[j] = (short)h;
    l8[j] = (short)bf16rne(vals[j] - bf2f(h));
  }
}
__device__ __forceinline__ f32x4 mfma16(short8 a, short8 b, f32x4 c) {
  return __builtin_amdgcn_mfma_f32_16x16x32_bf16(a, b, c, 0, 0, 0);
}

// ---------------------------------------------------------------------------
// K0: W [512][64] f32 -> W^T bf16 hi/lo in ws: [2][64 k][512 d]
// ---------------------------------------------------------------------------
__global__ __launch_bounds__(256) void k0_wt(const float* __restrict__ W,
                                             ushort* __restrict__ wsWT) {
  int k = blockIdx.x;  // 64
  for (int d = threadIdx.x; d < 512; d += 256) {
    float v = W[(size_t)d * 64 + k];
    ushort h = bf16rne(v);
    wsWT[k * 512 + d] = h;
    wsWT[32768 + k * 512 + d] = bf16rne(v - bf2f(h));
  }
}

// x B-fragment bundle for one 32-d step (6 float4 = 24 VGPR)
struct BF {
  float4 b00, b01, b10, b11, b20, b21;
};

// ---------------------------------------------------------------------------
// K1: per (n, r, third of 48 pixels): s^T = W^T * x, all fragments global->
// register (no staging barriers). 512 thr = 8 waves: wave w = (mi = w&3
// k-rows, dhalf = w>>2 d-half). Register-prefetch pipeline on x loads
// (issue step s+1 BEFORE MFMA of step s, in source order). Partial accs
// combined across wave-pairs via one LDS round, then softmax (waves 0-3)
// and a^T dump as in R5/R6. No inline asm anywhere.
// ---------------------------------------------------------------------------
__global__ __launch_bounds__(512, 6) void k1_assign(
    const float* __restrict__ x, const ushort* __restrict__ wsWT,
    float4* __restrict__ aT_ws, float* __restrict__ asum_ws) {
  __shared__ char sm[15872];
  ushort* atH = (ushort*)sm;              // [64 k][56-pad p]
  ushort* atL = (ushort*)(sm + 7168);
  float* accbuf = (float*)sm;             // overlay: [4 mi][64 lane][13]
  float* smax = (float*)(sm + 14336);     // [4 mi][48 p]
  float* ssum = (float*)(sm + 15104);

  int b = blockIdx.x;          // 864
  int region = b / 3, third = b % 3;
  int n = region / 9, r = region % 9;
  int y1 = (r / 3) * 12, x1 = (r % 3) * 12;
  int p0 = third * 48;
  int t = threadIdx.x;
  int w = t >> 6;
  int mi = w & 3, dhalf = w >> 2;
  int lane = t & 63, l15 = lane & 15, hi16 = lane >> 4;
  const float* xn = x + (size_t)n * (36 * 36 * 512);

  // per-lane x fragment base pointers (pixel by l15, d-subgroup by hi16)
  const float* pb0;
  const float* pb1;
  const float* pb2;
  {
    int pr0 = p0 + 0 * 16 + l15;
    int pr1 = p0 + 1 * 16 + l15;
    int pr2 = p0 + 2 * 16 + l15;
    pb0 = xn + ((size_t)(y1 + pr0 / 12) * 36 + (x1 + pr0 % 12)) * 512 + hi16 * 8;
    pb1 = xn + ((size_t)(y1 + pr1 / 12) * 36 + (x1 + pr1 % 12)) * 512 + hi16 * 8;
    pb2 = xn + ((size_t)(y1 + pr2 / 12) * 36 + (x1 + pr2 % 12)) * 512 + hi16 * 8;
  }
  const ushort* aBaseH = wsWT + (mi * 16 + l15) * 512 + hi16 * 8;
  const ushort* aBaseL = aBaseH + 32768;
  const int dbase = dhalf * 256;

  f32x4 acc[3];
#pragma unroll
  for (int ni = 0; ni < 3; ++ni) acc[ni] = (f32x4){0.f, 0.f, 0.f, 0.f};

  // prefetch step 0
  BF cur;
  cur.b00 = *(const float4*)(pb0 + dbase);
  cur.b01 = *(const float4*)(pb0 + dbase + 4);
  cur.b10 = *(const float4*)(pb1 + dbase);
  cur.b11 = *(const float4*)(pb1 + dbase + 4);
  cur.b20 = *(const float4*)(pb2 + dbase);
  cur.b21 = *(const float4*)(pb2 + dbase + 4);

#pragma unroll
  for (int s = 0; s < 8; ++s) {
    // issue next step's x loads FIRST (source order => no hoisting needed)
    BF nxt = cur;
    if (s < 7) {
      const int noff = dbase + (s + 1) * 32;
      nxt.b00 = *(const float4*)(pb0 + noff);
      nxt.b01 = *(const float4*)(pb0 + noff + 4);
      nxt.b10 = *(const float4*)(pb1 + noff);
      nxt.b11 = *(const float4*)(pb1 + noff + 4);
      nxt.b20 = *(const float4*)(pb2 + noff);
      nxt.b21 = *(const float4*)(pb2 + noff + 4);
    }
    // A-frags (W^T): L1/L2-hot, load at use
    const int off = dbase + s * 32;
    short8 aH = *(const short8*)(aBaseH + off);
    short8 aL = *(const short8*)(aBaseL + off);
    {
      short8 bH, bL;
      cvt8hl(cur.b00, cur.b01, bH, bL);
      f32x4 a0 = acc[0];
      a0 = mfma16(aH, bH, a0);
      a0 = mfma16(aH, bL, a0);
      a0 = mfma16(aL, bH, a0);
      acc[0] = a0;
    }
    {
      short8 bH, bL;
      cvt8hl(cur.b10, cur.b11, bH, bL);
      f32x4 a0 = acc[1];
      a0 = mfma16(aH, bH, a0);
      a0 = mfma16(aH, bL, a0);
      a0 = mfma16(aL, bH, a0);
      acc[1] = a0;
    }
    {
      short8 bH, bL;
      cvt8hl(cur.b20, cur.b21, bH, bL);
      f32x4 a0 = acc[2];
      a0 = mfma16(aH, bH, a0);
      a0 = mfma16(aH, bL, a0);
      a0 = mfma16(aL, bH, a0);
      acc[2] = a0;
    }
    cur = nxt;
  }

  // ---- combine wave-pair partial accumulators (dhalf 1 -> dhalf 0) ----
  if (dhalf == 1) {
    float* dst = accbuf + (mi * 64 + lane) * 13;
#pragma unroll
    for (int ni = 0; ni < 3; ++ni)
#pragma unroll
      for (int rr = 0; rr < 4; ++rr) dst[ni * 4 + rr] = acc[ni][rr];
  }
  __syncthreads();

  float lm[3], e[3][4], ls[3];
  if (dhalf == 0) {
    const float* src = accbuf + (mi * 64 + lane) * 13;
#pragma unroll
    for (int ni = 0; ni < 3; ++ni)
#pragma unroll
      for (int rr = 0; rr < 4; ++rr) acc[ni][rr] += src[ni * 4 + rr];

    // softmax over k: acc[ni][rr] = s[k = mi*16 + hi16*4 + rr][p = ni*16+l15]
#pragma unroll
    for (int ni = 0; ni < 3; ++ni) {
      float m = fmaxf(fmaxf(acc[ni][0], acc[ni][1]), fmaxf(acc[ni][2], acc[ni][3]));
      m = fmaxf(m, __shfl_xor(m, 16));
      m = fmaxf(m, __shfl_xor(m, 32));
      lm[ni] = m;
    }
    if (hi16 == 0)
#pragma unroll
      for (int ni = 0; ni < 3; ++ni) smax[mi * 48 + ni * 16 + l15] = lm[ni];
  }
  __syncthreads();

  if (dhalf == 0) {
#pragma unroll
    for (int ni = 0; ni < 3; ++ni) {
      int p = ni * 16 + l15;
      float M = fmaxf(fmaxf(smax[0 * 48 + p], smax[1 * 48 + p]),
                      fmaxf(smax[2 * 48 + p], smax[3 * 48 + p]));
      float s = 0.f;
#pragma unroll
      for (int rr = 0; rr < 4; ++rr) {
        e[ni][rr] = __expf(acc[ni][rr] - M);
        s += e[ni][rr];
      }
      s += __shfl_xor(s, 16);
      s += __shfl_xor(s, 32);
      ls[ni] = s;
    }
    if (hi16 == 0)
#pragma unroll
      for (int ni = 0; ni < 3; ++ni) ssum[mi * 48 + ni * 16 + l15] = ls[ni];
  }
  __syncthreads();

  if (dhalf == 0) {
    float part[4];
#pragma unroll
    for (int rr = 0; rr < 4; ++rr) part[rr] = 0.f;
#pragma unroll
    for (int ni = 0; ni < 3; ++ni) {
      int p = ni * 16 + l15;
      float S = ssum[0 * 48 + p] + ssum[1 * 48 + p] + ssum[2 * 48 + p] + ssum[3 * 48 + p];
      float inv = 1.f / S;
#pragma unroll
      for (int rr = 0; rr < 4; ++rr) {
        float a = e[ni][rr] * inv;
        part[rr] += a;
        int k = mi * 16 + hi16 * 4 + rr;
        ushort h = bf16rne(a);
        atH[k * 56 + p] = h;   // overwrites accbuf overlay: barrier-separated
        atL[k * 56 + p] = bf16rne(a - bf2f(h));
      }
    }
#pragma unroll
    for (int rr = 0; rr < 4; ++rr) {
      float s = part[rr];
      s += __shfl_xor(s, 1);
      s += __shfl_xor(s, 2);
      s += __shfl_xor(s, 4);
      s += __shfl_xor(s, 8);
      if (l15 == 0) asum_ws[b * 64 + mi * 16 + hi16 * 4 + rr] = s;
    }
  }
  __syncthreads();  // a^T LDS writes done

  // dump a^T to region slot [2][64][19 f4] at granule cols third*6..+5
  {
    float4* dst = aT_ws + (size_t)region * 2432;
    for (int i = t; i < 768; i += 512) {
      int plane = i / 384;
      int rem = i - plane * 384;
      int row = rem / 6, c4 = rem - row * 6;
      float4 v = *(const float4*)(sm + plane * 7168 + row * 112 + c4 * 16);
      dst[plane * 1216 + row * 19 + third * 6 + c4] = v;
    }
    if (third == 2) {
      float4 z = {0.f, 0.f, 0.f, 0.f};
      for (int i = t; i < 128; i += 512) {
        int plane = i >> 6, row = i & 63;
        dst[plane * 1216 + row * 19 + 18] = z;
      }
    }
  }
}

// ---------------------------------------------------------------------------
// K2: per (n,r,dc of 64): V = X^T * A - C*asum.  (R5 version, no inline asm)
// A-frags (x^T) loaded DIRECTLY global->register (transposed addressing via
// LDS poff table); B-frags (a^T) from linear-copied padded-152 LDS.
// colnorm^2 written to a private (reg,dc) slot — no atomics, no memset.
// ---------------------------------------------------------------------------
__global__ __launch_bounds__(512, 8) void k2_vlad(
    const float* __restrict__ x, const float* __restrict__ C,
    const float4* __restrict__ aT_ws, const float* __restrict__ asum_ws,
    float* __restrict__ out, float* __restrict__ colnorm) {
  __shared__ float4 smv[2504];               // 40064 B
  char* sm = (char*)smv;
  ushort* atH = (ushort*)sm;                 // [64 k][152 p]
  ushort* atL = (ushort*)(sm + 19456);
  int* poff = (int*)(sm + 38912);            // [160] pixel offsets (elements)
  float* asumS = (float*)(sm + 39552);
  float* cn2 = (float*)(sm + 39808);

  int b = blockIdx.x;          // 2304
  int reg = b % 288;           // XCD-swizzle: all 8 dc of a region -> same XCD
  int dc = b / 288;
  int n = reg / 9, r = reg % 9;
  int d0 = dc * 64;
  int y1 = (r / 3) * 12, x1 = (r % 3) * 12;
  int t = threadIdx.x;
  int w = t >> 6, lane = t & 63, l15 = lane & 15, hi16 = lane >> 4;
  const float* xn = x + (size_t)n * (36 * 36 * 512);

  if (t < 160) poff[t] = (t < 144) ? ((y1 + t / 12) * 36 + (x1 + t % 12)) * 512 : 0;
  if (t < 64) {
    asumS[t] = asum_ws[(reg * 3) * 64 + t] + asum_ws[(reg * 3 + 1) * 64 + t] +
               asum_ws[(reg * 3 + 2) * 64 + t];
    cn2[t] = 0.f;
  }
  {
    const float4* src = aT_ws + (size_t)reg * 2432;
    for (int i = t; i < 2432; i += 512) smv[i] = src[i];
  }
  __syncthreads();

  int mi = w & 3, kh = w >> 2;
  int drow = d0 + mi * 16 + l15;
  const float* xcol = xn + drow;

  f32x4 acc[2];
  acc[0] = (f32x4){0.f, 0.f, 0.f, 0.f};
  acc[1] = (f32x4){0.f, 0.f, 0.f, 0.f};

#pragma unroll
  for (int ks = 0; ks < 5; ++ks) {
    int pb = ks * 32 + hi16 * 8;
    int4 poA = *reinterpret_cast<const int4*>(&poff[pb]);
    int4 poB = *reinterpret_cast<const int4*>(&poff[pb + 4]);
    float av[8];
    av[0] = xcol[poA.x]; av[1] = xcol[poA.y];
    av[2] = xcol[poA.z]; av[3] = xcol[poA.w];
    av[4] = xcol[poB.x]; av[5] = xcol[poB.y];
    av[6] = xcol[poB.z]; av[7] = xcol[poB.w];
    bool valid = (ks < 4) || (hi16 < 2);   // p >= 144 -> zero A (kills product)
    short8 ah, al;
#pragma unroll
    for (int j = 0; j < 8; ++j) {
      float v = valid ? av[j] : 0.f;
      ushort h = bf16rne(v);
      ah[j] = (short)h;
      al[j] = (short)bf16rne(v - bf2f(h));
    }
#pragma unroll
    for (int ni = 0; ni < 2; ++ni) {
      int row = kh * 32 + ni * 16 + l15;
      short8 bh = *(const short8*)(atH + row * 152 + pb);
      short8 bl = *(const short8*)(atL + row * 152 + pb);
      f32x4 a0 = acc[ni];
      a0 = mfma16(ah, bh, a0);
      a0 = mfma16(ah, bl, a0);
      a0 = mfma16(al, bh, a0);
      acc[ni] = a0;
    }
  }

  size_t obase = (size_t)reg * (512 * 64);
#pragma unroll
  for (int ni = 0; ni < 2; ++ni) {
    int k = kh * 32 + ni * 16 + l15;
    float ak = asumS[k];
    float s2 = 0.f;
#pragma unroll
    for (int rr = 0; rr < 4; ++rr) {
      int d = d0 + mi * 16 + hi16 * 4 + rr;
      float v = acc[ni][rr] - C[(size_t)d * 64 + k] * ak;
      out[obase + (size_t)d * 64 + k] = v;
      s2 += v * v;
    }
    atomicAdd(&cn2[k], s2);
  }
  __syncthreads();
  if (t < 64) colnorm[(size_t)(reg * 8 + dc) * 64 + t] = cn2[t];
}

// ---------------------------------------------------------------------------
// K3: intra-norm + global-norm scaling in place (sums 8 partial colnorms).
// ---------------------------------------------------------------------------
__global__ __launch_bounds__(256) void k3_scale(float* __restrict__ out,
                                                const float* __restrict__ colnorm) {
  int b = blockIdx.x;  // 1152
  int reg = b % 288;   // match k2's writer XCD for L2 reuse
  int dc = b / 288;

  __shared__ float ratio[64];
  __shared__ float fs[64];
  int t = threadIdx.x;
  float c = 0.f;
  if (t < 64) {
#pragma unroll
    for (int j = 0; j < 8; ++j) c += colnorm[(size_t)(reg * 8 + j) * 64 + t];
    ratio[t] = c / (c + EPSF);
  }
  __syncthreads();
  if (t < 64) {
    float g = 0.f;
#pragma unroll
    for (int j = 0; j < 64; ++j) g += ratio[j];
    fs[t] = rsqrtf(c + EPSF) * rsqrtf(g + EPSF);
  }
  __syncthreads();

  size_t base4 = (((size_t)reg * 512) + (size_t)dc * 128) * 64 / 4;
  float4* o4 = reinterpret_cast<float4*>(out);
  for (int j = 0; j < 8; ++j) {
    size_t idx = base4 + t + 256 * j;
    float4 v = o4[idx];
    int k0 = (int)((idx * 4) & 63);
    v.x *= fs[k0]; v.y *= fs[k0 + 1]; v.z *= fs[k0 + 2]; v.w *= fs[k0 + 3];
    o4[idx] = v;
  }
}

extern "C" void kernel_launch(void* const* d_in, const int* in_sizes, int n_in,
                              void* d_out, int out_size, void* d_ws, size_t ws_size,
                              hipStream_t stream) {
  const float* x = (const float*)d_in[0];   // [32,36,36,512]
  const float* Wc = (const float*)d_in[1];  // [512,64]
  const float* C = (const float*)d_in[2];   // [512,64]
  float* out = (float*)d_out;

  char* ws = (char*)d_ws;
  ushort* wsWT = (ushort*)(ws);             // 131072 B
  float* asum_ws = (float*)(ws + 131072);   // 864*64*4 = 221184 B
  float* colnorm = (float*)(ws + 352256);   // 2304*64*4 = 589824 B
  float4* aT_ws = (float4*)(ws + 942080);   // 288 * 38912 B = 11.2 MB

  k0_wt<<<64, 256, 0, stream>>>(Wc, wsWT);
  k1_assign<<<864, 512, 0, stream>>>(x, wsWT, aT_ws, asum_ws);
  k2_vlad<<<2304, 512, 0, stream>>>(x, C, aT_ws, asum_ws, out, colnorm);
  k3_scale<<<1152, 256, 0, stream>>>(out, colnorm);
}

// Round 9
// 88.501 us; speedup vs baseline: 1.3225x; 1.3225x over previous
//
#include <hip/hip_runtime.h>

typedef __attribute__((ext_vector_type(4))) float f32x4;
typedef __attribute__((ext_vector_type(8))) short short8;

#define EPSF 1e-12f

__device__ __forceinline__ ushort bf16rne(float x) {
  uint u = __float_as_uint(x);
  u += 0x7fffu + ((u >> 16) & 1u);
  return (ushort)(u >> 16);
}
__device__ __forceinline__ float bf2f(ushort h) {
  return __uint_as_float(((uint)h) << 16);
}
// 8 floats -> hi/lo bf16 short8 pair (pure C: RNE hi, RNE residual lo)
__device__ __forceinline__ void cvt8hl(float4 v0, float4 v1, short8& h8, short8& l8) {
  float vals[8] = {v0.x, v0.y, v0.z, v0.w, v1.x, v1.y, v1.z, v1.w};
#pragma unroll
  for (int j = 0; j < 8; ++j) {
    ushort h = bf16rne(vals[j]);
    h8[j] = (short)h;
    l8[j] = (short)bf16rne(vals[j] - bf2f(h));
  }
}
__device__ __forceinline__ f32x4 mfma16(short8 a, short8 b, f32x4 c) {
  return __builtin_amdgcn_mfma_f32_16x16x32_bf16(a, b, c, 0, 0, 0);
}

// ---------------------------------------------------------------------------
// K0: W [512][64] f32 -> fragment-major W^T bf16 hi/lo:
//   ws2[plane][s2][mi][lane l][j]  (plane stride 32768 ushorts = 64KB)
//   element = W^T(k = mi*16 + (l&15), d = s2*32 + (l>>4)*8 + j)
// so a k1 wave's A-frag is ONE contiguous 1KB short8 load.
// ---------------------------------------------------------------------------
__global__ __launch_bounds__(256) void k0_wt(const float* __restrict__ W,
                                             ushort* __restrict__ ws2) {
  int k = blockIdx.x;  // 64
  int mi = k >> 4, l15k = k & 15;
  for (int task = threadIdx.x; task < 512; task += 256) {
    int dg8 = task >> 3, j = task & 7;   // dg8 = d>>3
    int d = dg8 * 8 + j;
    int s2 = dg8 >> 2, hi16d = dg8 & 3;
    int l = hi16d * 16 + l15k;
    float v = W[(size_t)d * 64 + k];
    ushort h = bf16rne(v);
    size_t idx = ((size_t)(s2 * 4 + mi) * 64 + l) * 8 + j;
    ws2[idx] = h;
    ws2[32768 + idx] = bf16rne(v - bf2f(h));
  }
}

// ---------------------------------------------------------------------------
// K1: per (n, r, third of 48 pixels): s^T = W^T * x.
// x staged per 64-d chunk as f32 into LDS: LINEAR ds_write (granule = task id),
// XOR swizzle carried on the GLOBAL source address (m173 pattern):
//   task G: p = G>>4, sgS = G&15, content dg = (sgS&8)|((sgS&7)^(p&7)).
// Fragment read applies the same involution -> conflict-free-ish (2-way).
// T14 pipeline: barrier / ds_write(c) / barrier / gload(c+1) / compute(c)
// so the global loads stay in flight across compute. A-frags = contiguous
// short8 from fragment-major ws2 (L2-hot). 8 waves = (mi = w&3, ks = w>>2).
// Epilogue (accbuf combine + cross-wave softmax + a^T dump) as in R7.
// ---------------------------------------------------------------------------
__global__ __launch_bounds__(512, 4) void k1_assign(
    const float* __restrict__ x, const ushort* __restrict__ ws2,
    float4* __restrict__ aT_ws, float* __restrict__ asum_ws) {
  __shared__ char sm[26112];
  float4* buf = (float4*)sm;              // [2][768] 16B granules (24576 B)
  ushort* atH = (ushort*)sm;              // overlay: [64 k][56-pad p]
  ushort* atL = (ushort*)(sm + 7168);
  float* accbuf = (float*)sm;             // overlay: [4 mi][64 lane][13]
  float* smax = (float*)(sm + 24576);     // [4 mi][48 p]
  float* ssum = (float*)(sm + 25344);

  int b = blockIdx.x;          // 864
  int region = b / 3, third = b % 3;
  int n = region / 9, r = region % 9;
  int y1 = (r / 3) * 12, x1 = (r % 3) * 12;
  int p0 = third * 48;
  int t = threadIdx.x;
  int w = t >> 6;
  int mi = w & 3, ks = w >> 2;   // wave owns 16 k-rows x one 32-d half/chunk
  int lane = t & 63, l15 = lane & 15, hi16 = lane >> 4;
  const float* xn = x + (size_t)n * (36 * 36 * 512);

  // staging source pointers for this thread's tasks (G0 = t, G1 = 512+t)
  const float* srcA;
  const float* srcB = nullptr;
  {
    int G = t;
    int p = G >> 4, sgS = G & 15;
    int dg = (sgS & 8) | ((sgS & 7) ^ (p & 7));
    int pr = p0 + p;
    srcA = xn + ((size_t)(y1 + pr / 12) * 36 + (x1 + pr % 12)) * 512 + dg * 4;
  }
  if (t < 256) {
    int G = 512 + t;
    int p = G >> 4, sgS = G & 15;
    int dg = (sgS & 8) | ((sgS & 7) ^ (p & 7));
    int pr = p0 + p;
    srcB = xn + ((size_t)(y1 + pr / 12) * 36 + (x1 + pr % 12)) * 512 + dg * 4;
  }

  f32x4 acc[3];
#pragma unroll
  for (int ni = 0; ni < 3; ++ni) acc[ni] = (f32x4){0.f, 0.f, 0.f, 0.f};

  // prefetch chunk 0 into registers
  float4 ra = *(const float4*)srcA;
  float4 rb = (t < 256) ? *(const float4*)srcB : ra;

  for (int c = 0; c < 8; ++c) {
    __syncthreads();   // buf[c&1] free (readers of it were compute(c-2));
                       // also drains vmcnt -> ra/rb valid
    float4* bufc = buf + (size_t)(c & 1) * 768;
    bufc[t] = ra;
    if (t < 256) bufc[512 + t] = rb;
    __syncthreads();   // ds_writes visible
    if (c < 7) {       // issue next chunk loads AFTER the barrier: they stay
                       // in flight across compute(c), drain at next barrier
      ra = *(const float4*)(srcA + (c + 1) * 64);
      if (t < 256) rb = *(const float4*)(srcB + (c + 1) * 64);
    }
    // ---- compute chunk c: this wave's ks half (32 d) ----
    const ushort* aPtr = ws2 + ((size_t)((c * 2 + ks) * 4 + mi) * 64 + lane) * 8;
    short8 aH = *(const short8*)aPtr;
    short8 aL = *(const short8*)(aPtr + 32768);
    int dg0 = ks * 8 + hi16 * 2;
#pragma unroll
    for (int ni = 0; ni < 3; ++ni) {
      int p = ni * 16 + l15;
      int sg0 = (dg0 & 8) | ((dg0 & 7) ^ (p & 7));
      float4 lo = bufc[p * 16 + sg0];
      float4 hi = bufc[p * 16 + (sg0 ^ 1)];
      short8 bH, bL;
      cvt8hl(lo, hi, bH, bL);
      f32x4 a0 = acc[ni];
      a0 = mfma16(aH, bH, a0);
      a0 = mfma16(aH, bL, a0);
      a0 = mfma16(aL, bH, a0);
      acc[ni] = a0;
    }
  }
  __syncthreads();   // all compute(7) LDS reads done -> overlays safe

  // ---- combine wave-pair partial accumulators (ks 1 -> ks 0) ----
  if (ks == 1) {
    float* dst = accbuf + (mi * 64 + lane) * 13;
#pragma unroll
    for (int ni = 0; ni < 3; ++ni)
#pragma unroll
      for (int rr = 0; rr < 4; ++rr) dst[ni * 4 + rr] = acc[ni][rr];
  }
  __syncthreads();

  float lm[3], e[3][4], ls[3];
  if (ks == 0) {
    const float* src = accbuf + (mi * 64 + lane) * 13;
#pragma unroll
    for (int ni = 0; ni < 3; ++ni)
#pragma unroll
      for (int rr = 0; rr < 4; ++rr) acc[ni][rr] += src[ni * 4 + rr];

    // softmax over k: acc[ni][rr] = s[k = mi*16 + hi16*4 + rr][p = ni*16+l15]
#pragma unroll
    for (int ni = 0; ni < 3; ++ni) {
      float m = fmaxf(fmaxf(acc[ni][0], acc[ni][1]), fmaxf(acc[ni][2], acc[ni][3]));
      m = fmaxf(m, __shfl_xor(m, 16));
      m = fmaxf(m, __shfl_xor(m, 32));
      lm[ni] = m;
    }
    if (hi16 == 0)
#pragma unroll
      for (int ni = 0; ni < 3; ++ni) smax[mi * 48 + ni * 16 + l15] = lm[ni];
  }
  __syncthreads();

  if (ks == 0) {
#pragma unroll
    for (int ni = 0; ni < 3; ++ni) {
      int p = ni * 16 + l15;
      float M = fmaxf(fmaxf(smax[0 * 48 + p], smax[1 * 48 + p]),
                      fmaxf(smax[2 * 48 + p], smax[3 * 48 + p]));
      float s = 0.f;
#pragma unroll
      for (int rr = 0; rr < 4; ++rr) {
        e[ni][rr] = __expf(acc[ni][rr] - M);
        s += e[ni][rr];
      }
      s += __shfl_xor(s, 16);
      s += __shfl_xor(s, 32);
      ls[ni] = s;
    }
    if (hi16 == 0)
#pragma unroll
      for (int ni = 0; ni < 3; ++ni) ssum[mi * 48 + ni * 16 + l15] = ls[ni];
  }
  __syncthreads();

  if (ks == 0) {
    float part[4];
#pragma unroll
    for (int rr = 0; rr < 4; ++rr) part[rr] = 0.f;
#pragma unroll
    for (int ni = 0; ni < 3; ++ni) {
      int p = ni * 16 + l15;
      float S = ssum[0 * 48 + p] + ssum[1 * 48 + p] + ssum[2 * 48 + p] + ssum[3 * 48 + p];
      float inv = 1.f / S;
#pragma unroll
      for (int rr = 0; rr < 4; ++rr) {
        float a = e[ni][rr] * inv;
        part[rr] += a;
        int k = mi * 16 + hi16 * 4 + rr;
        ushort h = bf16rne(a);
        atH[k * 56 + p] = h;   // overlays accbuf: reads were 2 barriers ago
        atL[k * 56 + p] = bf16rne(a - bf2f(h));
      }
    }
#pragma unroll
    for (int rr = 0; rr < 4; ++rr) {
      float s = part[rr];
      s += __shfl_xor(s, 1);
      s += __shfl_xor(s, 2);
      s += __shfl_xor(s, 4);
      s += __shfl_xor(s, 8);
      if (l15 == 0) asum_ws[b * 64 + mi * 16 + hi16 * 4 + rr] = s;
    }
  }
  __syncthreads();  // a^T LDS writes done

  // dump a^T to region slot [2][64][19 f4] at granule cols third*6..+5
  {
    float4* dst = aT_ws + (size_t)region * 2432;
    for (int i = t; i < 768; i += 512) {
      int plane = i / 384;
      int rem = i - plane * 384;
      int row = rem / 6, c4 = rem - row * 6;
      float4 v = *(const float4*)(sm + plane * 7168 + row * 112 + c4 * 16);
      dst[plane * 1216 + row * 19 + third * 6 + c4] = v;
    }
    if (third == 2) {
      float4 z = {0.f, 0.f, 0.f, 0.f};
      for (int i = t; i < 128; i += 512) {
        int plane = i >> 6, row = i & 63;
        dst[plane * 1216 + row * 19 + 18] = z;
      }
    }
  }
}

// ---------------------------------------------------------------------------
// K2: per (n,r,dc of 64): V = X^T * A - C*asum.  (unchanged, proven ~15us)
// ---------------------------------------------------------------------------
__global__ __launch_bounds__(512, 8) void k2_vlad(
    const float* __restrict__ x, const float* __restrict__ C,
    const float4* __restrict__ aT_ws, const float* __restrict__ asum_ws,
    float* __restrict__ out, float* __restrict__ colnorm) {
  __shared__ float4 smv[2504];               // 40064 B
  char* sm = (char*)smv;
  ushort* atH = (ushort*)sm;                 // [64 k][152 p]
  ushort* atL = (ushort*)(sm + 19456);
  int* poff = (int*)(sm + 38912);            // [160] pixel offsets (elements)
  float* asumS = (float*)(sm + 39552);
  float* cn2 = (float*)(sm + 39808);

  int b = blockIdx.x;          // 2304
  int reg = b % 288;           // XCD-swizzle: all 8 dc of a region -> same XCD
  int dc = b / 288;
  int n = reg / 9, r = reg % 9;
  int d0 = dc * 64;
  int y1 = (r / 3) * 12, x1 = (r % 3) * 12;
  int t = threadIdx.x;
  int w = t >> 6, lane = t & 63, l15 = lane & 15, hi16 = lane >> 4;
  const float* xn = x + (size_t)n * (36 * 36 * 512);

  if (t < 160) poff[t] = (t < 144) ? ((y1 + t / 12) * 36 + (x1 + t % 12)) * 512 : 0;
  if (t < 64) {
    asumS[t] = asum_ws[(reg * 3) * 64 + t] + asum_ws[(reg * 3 + 1) * 64 + t] +
               asum_ws[(reg * 3 + 2) * 64 + t];
    cn2[t] = 0.f;
  }
  {
    const float4* src = aT_ws + (size_t)reg * 2432;
    for (int i = t; i < 2432; i += 512) smv[i] = src[i];
  }
  __syncthreads();

  int mi = w & 3, kh = w >> 2;
  int drow = d0 + mi * 16 + l15;
  const float* xcol = xn + drow;

  f32x4 acc[2];
  acc[0] = (f32x4){0.f, 0.f, 0.f, 0.f};
  acc[1] = (f32x4){0.f, 0.f, 0.f, 0.f};

#pragma unroll
  for (int ks = 0; ks < 5; ++ks) {
    int pb = ks * 32 + hi16 * 8;
    int4 poA = *reinterpret_cast<const int4*>(&poff[pb]);
    int4 poB = *reinterpret_cast<const int4*>(&poff[pb + 4]);
    float av[8];
    av[0] = xcol[poA.x]; av[1] = xcol[poA.y];
    av[2] = xcol[poA.z]; av[3] = xcol[poA.w];
    av[4] = xcol[poB.x]; av[5] = xcol[poB.y];
    av[6] = xcol[poB.z]; av[7] = xcol[poB.w];
    bool valid = (ks < 4) || (hi16 < 2);   // p >= 144 -> zero A (kills product)
    short8 ah, al;
#pragma unroll
    for (int j = 0; j < 8; ++j) {
      float v = valid ? av[j] : 0.f;
      ushort h = bf16rne(v);
      ah[j] = (short)h;
      al[j] = (short)bf16rne(v - bf2f(h));
    }
#pragma unroll
    for (int ni = 0; ni < 2; ++ni) {
      int row = kh * 32 + ni * 16 + l15;
      short8 bh = *(const short8*)(atH + row * 152 + pb);
      short8 bl = *(const short8*)(atL + row * 152 + pb);
      f32x4 a0 = acc[ni];
      a0 = mfma16(ah, bh, a0);
      a0 = mfma16(ah, bl, a0);
      a0 = mfma16(al, bh, a0);
      acc[ni] = a0;
    }
  }

  size_t obase = (size_t)reg * (512 * 64);
#pragma unroll
  for (int ni = 0; ni < 2; ++ni) {
    int k = kh * 32 + ni * 16 + l15;
    float ak = asumS[k];
    float s2 = 0.f;
#pragma unroll
    for (int rr = 0; rr < 4; ++rr) {
      int d = d0 + mi * 16 + hi16 * 4 + rr;
      float v = acc[ni][rr] - C[(size_t)d * 64 + k] * ak;
      out[obase + (size_t)d * 64 + k] = v;
      s2 += v * v;
    }
    atomicAdd(&cn2[k], s2);
  }
  __syncthreads();
  if (t < 64) colnorm[(size_t)(reg * 8 + dc) * 64 + t] = cn2[t];
}

// ---------------------------------------------------------------------------
// K3: intra-norm + global-norm scaling in place (sums 8 partial colnorms).
// ---------------------------------------------------------------------------
__global__ __launch_bounds__(256) void k3_scale(float* __restrict__ out,
                                                const float* __restrict__ colnorm) {
  int b = blockIdx.x;  // 1152
  int reg = b % 288;   // match k2's writer XCD for L2 reuse
  int dc = b / 288;

  __shared__ float ratio[64];
  __shared__ float fs[64];
  int t = threadIdx.x;
  float c = 0.f;
  if (t < 64) {
#pragma unroll
    for (int j = 0; j < 8; ++j) c += colnorm[(size_t)(reg * 8 + j) * 64 + t];
    ratio[t] = c / (c + EPSF);
  }
  __syncthreads();
  if (t < 64) {
    float g = 0.f;
#pragma unroll
    for (int j = 0; j < 64; ++j) g += ratio[j];
    fs[t] = rsqrtf(c + EPSF) * rsqrtf(g + EPSF);
  }
  __syncthreads();

  size_t base4 = (((size_t)reg * 512) + (size_t)dc * 128) * 64 / 4;
  float4* o4 = reinterpret_cast<float4*>(out);
  for (int j = 0; j < 8; ++j) {
    size_t idx = base4 + t + 256 * j;
    float4 v = o4[idx];
    int k0 = (int)((idx * 4) & 63);
    v.x *= fs[k0]; v.y *= fs[k0 + 1]; v.z *= fs[k0 + 2]; v.w *= fs[k0 + 3];
    o4[idx] = v;
  }
}

extern "C" void kernel_launch(void* const* d_in, const int* in_sizes, int n_in,
                              void* d_out, int out_size, void* d_ws, size_t ws_size,
                              hipStream_t stream) {
  const float* x = (const float*)d_in[0];   // [32,36,36,512]
  const float* Wc = (const float*)d_in[1];  // [512,64]
  const float* C = (const float*)d_in[2];   // [512,64]
  float* out = (float*)d_out;

  char* ws = (char*)d_ws;
  ushort* ws2 = (ushort*)(ws);              // 131072 B (2 x 64KB planes)
  float* asum_ws = (float*)(ws + 131072);   // 864*64*4 = 221184 B
  float* colnorm = (float*)(ws + 352256);   // 2304*64*4 = 589824 B
  float4* aT_ws = (float4*)(ws + 942080);   // 288 * 38912 B = 11.2 MB

  k0_wt<<<64, 256, 0, stream>>>(Wc, ws2);
  k1_assign<<<864, 512, 0, stream>>>(x, ws2, aT_ws, asum_ws);
  k2_vlad<<<2304, 512, 0, stream>>>(x, C, aT_ws, asum_ws, out, colnorm);
  k3_scale<<<1152, 256, 0, stream>>>(out, colnorm);
}

// Round 10
// 88.257 us; speedup vs baseline: 1.3261x; 1.0028x over previous
//
#include <hip/hip_runtime.h>

typedef __attribute__((ext_vector_type(4))) float f32x4;
typedef __attribute__((ext_vector_type(8))) short short8;

#define EPSF 1e-12f

__device__ __forceinline__ ushort bf16rne(float x) {
  uint u = __float_as_uint(x);
  u += 0x7fffu + ((u >> 16) & 1u);
  return (ushort)(u >> 16);
}
__device__ __forceinline__ float bf2f(ushort h) {
  return __uint_as_float(((uint)h) << 16);
}
// 8 floats -> hi/lo bf16 short8 pair (pure C: RNE hi, RNE residual lo)
__device__ __forceinline__ void cvt8hl(float4 v0, float4 v1, short8& h8, short8& l8) {
  float vals[8] = {v0.x, v0.y, v0.z, v0.w, v1.x, v1.y, v1.z, v1.w};
#pragma unroll
  for (int j = 0; j < 8; ++j) {
    ushort h = bf16rne(vals[j]);
    h8[j] = (short)h;
    l8[j] = (short)bf16rne(vals[j] - bf2f(h));
  }
}
__device__ __forceinline__ f32x4 mfma16(short8 a, short8 b, f32x4 c) {
  return __builtin_amdgcn_mfma_f32_16x16x32_bf16(a, b, c, 0, 0, 0);
}
// async global->LDS, 16B per lane; lds dest = wave-uniform base + lane*16
__device__ __forceinline__ void gl_lds16(const float* src, char* ldsbase) {
  __builtin_amdgcn_global_load_lds(
      (const __attribute__((address_space(1))) unsigned int*)src,
      (__attribute__((address_space(3))) unsigned int*)ldsbase, 16, 0, 0);
}

// ---------------------------------------------------------------------------
// K0: W [512][64] f32 -> fragment-major W^T bf16 hi/lo:
//   ws2[plane][s2][mi][lane l][j]  (plane stride 32768 ushorts = 64KB)
//   element = W^T(k = mi*16 + (l&15), d = s2*32 + (l>>4)*8 + j)
// so a k1 wave's A-frag is ONE contiguous 1KB short8 load.
// ---------------------------------------------------------------------------
__global__ __launch_bounds__(256) void k0_wt(const float* __restrict__ W,
                                             ushort* __restrict__ ws2) {
  int k = blockIdx.x;  // 64
  int mi = k >> 4, l15k = k & 15;
  for (int task = threadIdx.x; task < 512; task += 256) {
    int dg8 = task >> 3, j = task & 7;   // dg8 = d>>3
    int d = dg8 * 8 + j;
    int s2 = dg8 >> 2, hi16d = dg8 & 3;
    int l = hi16d * 16 + l15k;
    float v = W[(size_t)d * 64 + k];
    ushort h = bf16rne(v);
    size_t idx = ((size_t)(s2 * 4 + mi) * 64 + l) * 8 + j;
    ws2[idx] = h;
    ws2[32768 + idx] = bf16rne(v - bf2f(h));
  }
}

// ---------------------------------------------------------------------------
// K1: per (n, r, third of 48 pixels): s^T = W^T * x.
// x staged per 64-d chunk via global_load_lds (async DMA, no VGPR roundtrip):
// LINEAR LDS dest (task = p*16 + sg, 16B granules), XOR swizzle carried on
// the GLOBAL source address: task (p,sg) fetches dg = (sg&8)|((sg&7)^(p&7)).
// 2-phase schedule (T3 minimum): issue(c+1) -> compute(c) -> __syncthreads().
// A-frags = contiguous short8 from fragment-major ws2 (L2-hot).
// 8 waves = (mi = w&3, ks = w>>2); waves 0-5 stage (2 gload_lds each).
// Epilogue (accbuf combine + cross-wave softmax + a^T dump) as in R8.
// ---------------------------------------------------------------------------
__global__ __launch_bounds__(512, 8) void k1_assign(
    const float* __restrict__ x, const ushort* __restrict__ ws2,
    float4* __restrict__ aT_ws, float* __restrict__ asum_ws) {
  __shared__ char sm[26112];
  // buf[2][768] float4 granules (24576 B); overlays after the MFMA loop:
  ushort* atH = (ushort*)sm;              // [64 k][56-pad p]
  ushort* atL = (ushort*)(sm + 7168);
  float* accbuf = (float*)sm;             // [4 mi][64 lane][13]
  float* smax = (float*)(sm + 24576);     // [4 mi][48 p]
  float* ssum = (float*)(sm + 25344);

  int b = blockIdx.x;          // 864
  int region = b / 3, third = b % 3;
  int n = region / 9, r = region % 9;
  int y1 = (r / 3) * 12, x1 = (r % 3) * 12;
  int p0 = third * 48;
  int t = threadIdx.x;
  int w = t >> 6;
  int mi = w & 3, ks = w >> 2;   // wave owns 16 k-rows x one 32-d half/chunk
  int lane = t & 63, l15 = lane & 15, hi16 = lane >> 4;
  const float* xn = x + (size_t)n * (36 * 36 * 512);

  // staging sources for this thread's (up to) 2 tasks; chunk-0 addresses.
  // task T = (w*2+i)*64 + lane: p = T>>4, sg = T&15, dg = (sg&8)|((sg&7)^(p&7))
  const float* sA[2] = {nullptr, nullptr};
  int ldsrow[2] = {0, 0};
  if (w < 6) {
#pragma unroll
    for (int i = 0; i < 2; ++i) {
      int T = (w * 2 + i) * 64 + lane;
      int p = T >> 4, sg = T & 15;
      int dg = (sg & 8) | ((sg & 7) ^ (p & 7));
      int pr = p0 + p;
      sA[i] = xn + ((size_t)(y1 + pr / 12) * 36 + (x1 + pr % 12)) * 512 + dg * 4;
      ldsrow[i] = (w * 2 + i) * 64;   // wave-uniform row base (in granules)
    }
  }

  f32x4 acc[3];
#pragma unroll
  for (int ni = 0; ni < 3; ++ni) acc[ni] = (f32x4){0.f, 0.f, 0.f, 0.f};

  // prologue: stage chunk 0 into buf[0]
  if (w < 6) {
    gl_lds16(sA[0], sm + ldsrow[0] * 16);
    gl_lds16(sA[1], sm + ldsrow[1] * 16);
  }
  __syncthreads();

  for (int c = 0; c < 8; ++c) {
    char* bufc = sm + (c & 1) * 12288;
    // issue next chunk's async loads into the other buffer (overlap compute)
    if (c < 7 && w < 6) {
      char* bufn = sm + ((c + 1) & 1) * 12288;
      gl_lds16(sA[0] + (c + 1) * 64, bufn + ldsrow[0] * 16);
      gl_lds16(sA[1] + (c + 1) * 64, bufn + ldsrow[1] * 16);
    }
    // ---- compute chunk c: this wave's ks half (32 d) ----
    const ushort* aPtr = ws2 + ((size_t)((c * 2 + ks) * 4 + mi) * 64 + lane) * 8;
    short8 aH = *(const short8*)aPtr;
    short8 aL = *(const short8*)(aPtr + 32768);
    int dg0 = ks * 8 + hi16 * 2;
#pragma unroll
    for (int ni = 0; ni < 3; ++ni) {
      int p = ni * 16 + l15;
      int sg0 = (dg0 & 8) | ((dg0 & 7) ^ (p & 7));
      const float4* row = (const float4*)bufc + p * 16;
      float4 lo = row[sg0];
      float4 hi = row[sg0 ^ 1];
      short8 bH, bL;
      cvt8hl(lo, hi, bH, bL);
      f32x4 a0 = acc[ni];
      a0 = mfma16(aH, bH, a0);
      a0 = mfma16(aH, bL, a0);
      a0 = mfma16(aL, bH, a0);
      acc[ni] = a0;
    }
    __syncthreads();   // drains this wave's async loads (vmcnt 0) + syncs
  }

  // ---- combine wave-pair partial accumulators (ks 1 -> ks 0) ----
  if (ks == 1) {
    float* dst = accbuf + (mi * 64 + lane) * 13;
#pragma unroll
    for (int ni = 0; ni < 3; ++ni)
#pragma unroll
      for (int rr = 0; rr < 4; ++rr) dst[ni * 4 + rr] = acc[ni][rr];
  }
  __syncthreads();

  float lm[3], e[3][4], ls[3];
  if (ks == 0) {
    const float* src = accbuf + (mi * 64 + lane) * 13;
#pragma unroll
    for (int ni = 0; ni < 3; ++ni)
#pragma unroll
      for (int rr = 0; rr < 4; ++rr) acc[ni][rr] += src[ni * 4 + rr];

    // softmax over k: acc[ni][rr] = s[k = mi*16 + hi16*4 + rr][p = ni*16+l15]
#pragma unroll
    for (int ni = 0; ni < 3; ++ni) {
      float m = fmaxf(fmaxf(acc[ni][0], acc[ni][1]), fmaxf(acc[ni][2], acc[ni][3]));
      m = fmaxf(m, __shfl_xor(m, 16));
      m = fmaxf(m, __shfl_xor(m, 32));
      lm[ni] = m;
    }
    if (hi16 == 0)
#pragma unroll
      for (int ni = 0; ni < 3; ++ni) smax[mi * 48 + ni * 16 + l15] = lm[ni];
  }
  __syncthreads();

  if (ks == 0) {
#pragma unroll
    for (int ni = 0; ni < 3; ++ni) {
      int p = ni * 16 + l15;
      float M = fmaxf(fmaxf(smax[0 * 48 + p], smax[1 * 48 + p]),
                      fmaxf(smax[2 * 48 + p], smax[3 * 48 + p]));
      float s = 0.f;
#pragma unroll
      for (int rr = 0; rr < 4; ++rr) {
        e[ni][rr] = __expf(acc[ni][rr] - M);
        s += e[ni][rr];
      }
      s += __shfl_xor(s, 16);
      s += __shfl_xor(s, 32);
      ls[ni] = s;
    }
    if (hi16 == 0)
#pragma unroll
      for (int ni = 0; ni < 3; ++ni) ssum[mi * 48 + ni * 16 + l15] = ls[ni];
  }
  __syncthreads();

  if (ks == 0) {
    float part[4];
#pragma unroll
    for (int rr = 0; rr < 4; ++rr) part[rr] = 0.f;
#pragma unroll
    for (int ni = 0; ni < 3; ++ni) {
      int p = ni * 16 + l15;
      float S = ssum[0 * 48 + p] + ssum[1 * 48 + p] + ssum[2 * 48 + p] + ssum[3 * 48 + p];
      float inv = 1.f / S;
#pragma unroll
      for (int rr = 0; rr < 4; ++rr) {
        float a = e[ni][rr] * inv;
        part[rr] += a;
        int k = mi * 16 + hi16 * 4 + rr;
        ushort h = bf16rne(a);
        atH[k * 56 + p] = h;   // overlays accbuf: its reads were 2 barriers ago
        atL[k * 56 + p] = bf16rne(a - bf2f(h));
      }
    }
#pragma unroll
    for (int rr = 0; rr < 4; ++rr) {
      float s = part[rr];
      s += __shfl_xor(s, 1);
      s += __shfl_xor(s, 2);
      s += __shfl_xor(s, 4);
      s += __shfl_xor(s, 8);
      if (l15 == 0) asum_ws[b * 64 + mi * 16 + hi16 * 4 + rr] = s;
    }
  }
  __syncthreads();  // a^T LDS writes done

  // dump a^T to region slot [2][64][19 f4] at granule cols third*6..+5
  {
    float4* dst = aT_ws + (size_t)region * 2432;
    for (int i = t; i < 768; i += 512) {
      int plane = i / 384;
      int rem = i - plane * 384;
      int row = rem / 6, c4 = rem - row * 6;
      float4 v = *(const float4*)(sm + plane * 7168 + row * 112 + c4 * 16);
      dst[plane * 1216 + row * 19 + third * 6 + c4] = v;
    }
    if (third == 2) {
      float4 z = {0.f, 0.f, 0.f, 0.f};
      for (int i = t; i < 128; i += 512) {
        int plane = i >> 6, row = i & 63;
        dst[plane * 1216 + row * 19 + 18] = z;
      }
    }
  }
}

// ---------------------------------------------------------------------------
// K2: per (n,r,dc of 64): V = X^T * A - C*asum.  (unchanged, proven)
// ---------------------------------------------------------------------------
__global__ __launch_bounds__(512, 8) void k2_vlad(
    const float* __restrict__ x, const float* __restrict__ C,
    const float4* __restrict__ aT_ws, const float* __restrict__ asum_ws,
    float* __restrict__ out, float* __restrict__ colnorm) {
  __shared__ float4 smv[2504];               // 40064 B
  char* sm = (char*)smv;
  ushort* atH = (ushort*)sm;                 // [64 k][152 p]
  ushort* atL = (ushort*)(sm + 19456);
  int* poff = (int*)(sm + 38912);            // [160] pixel offsets (elements)
  float* asumS = (float*)(sm + 39552);
  float* cn2 = (float*)(sm + 39808);

  int b = blockIdx.x;          // 2304
  int reg = b % 288;           // XCD-swizzle: all 8 dc of a region -> same XCD
  int dc = b / 288;
  int n = reg / 9, r = reg % 9;
  int d0 = dc * 64;
  int y1 = (r / 3) * 12, x1 = (r % 3) * 12;
  int t = threadIdx.x;
  int w = t >> 6, lane = t & 63, l15 = lane & 15, hi16 = lane >> 4;
  const float* xn = x + (size_t)n * (36 * 36 * 512);

  if (t < 160) poff[t] = (t < 144) ? ((y1 + t / 12) * 36 + (x1 + t % 12)) * 512 : 0;
  if (t < 64) {
    asumS[t] = asum_ws[(reg * 3) * 64 + t] + asum_ws[(reg * 3 + 1) * 64 + t] +
               asum_ws[(reg * 3 + 2) * 64 + t];
    cn2[t] = 0.f;
  }
  {
    const float4* src = aT_ws + (size_t)reg * 2432;
    for (int i = t; i < 2432; i += 512) smv[i] = src[i];
  }
  __syncthreads();

  int mi = w & 3, kh = w >> 2;
  int drow = d0 + mi * 16 + l15;
  const float* xcol = xn + drow;

  f32x4 acc[2];
  acc[0] = (f32x4){0.f, 0.f, 0.f, 0.f};
  acc[1] = (f32x4){0.f, 0.f, 0.f, 0.f};

#pragma unroll
  for (int ks = 0; ks < 5; ++ks) {
    int pb = ks * 32 + hi16 * 8;
    int4 poA = *reinterpret_cast<const int4*>(&poff[pb]);
    int4 poB = *reinterpret_cast<const int4*>(&poff[pb + 4]);
    float av[8];
    av[0] = xcol[poA.x]; av[1] = xcol[poA.y];
    av[2] = xcol[poA.z]; av[3] = xcol[poA.w];
    av[4] = xcol[poB.x]; av[5] = xcol[poB.y];
    av[6] = xcol[poB.z]; av[7] = xcol[poB.w];
    bool valid = (ks < 4) || (hi16 < 2);   // p >= 144 -> zero A (kills product)
    short8 ah, al;
#pragma unroll
    for (int j = 0; j < 8; ++j) {
      float v = valid ? av[j] : 0.f;
      ushort h = bf16rne(v);
      ah[j] = (short)h;
      al[j] = (short)bf16rne(v - bf2f(h));
    }
#pragma unroll
    for (int ni = 0; ni < 2; ++ni) {
      int row = kh * 32 + ni * 16 + l15;
      short8 bh = *(const short8*)(atH + row * 152 + pb);
      short8 bl = *(const short8*)(atL + row * 152 + pb);
      f32x4 a0 = acc[ni];
      a0 = mfma16(ah, bh, a0);
      a0 = mfma16(ah, bl, a0);
      a0 = mfma16(al, bh, a0);
      acc[ni] = a0;
    }
  }

  size_t obase = (size_t)reg * (512 * 64);
#pragma unroll
  for (int ni = 0; ni < 2; ++ni) {
    int k = kh * 32 + ni * 16 + l15;
    float ak = asumS[k];
    float s2 = 0.f;
#pragma unroll
    for (int rr = 0; rr < 4; ++rr) {
      int d = d0 + mi * 16 + hi16 * 4 + rr;
      float v = acc[ni][rr] - C[(size_t)d * 64 + k] * ak;
      out[obase + (size_t)d * 64 + k] = v;
      s2 += v * v;
    }
    atomicAdd(&cn2[k], s2);
  }
  __syncthreads();
  if (t < 64) colnorm[(size_t)(reg * 8 + dc) * 64 + t] = cn2[t];
}

// ---------------------------------------------------------------------------
// K3: intra-norm + global-norm scaling in place (sums 8 partial colnorms).
// ---------------------------------------------------------------------------
__global__ __launch_bounds__(256) void k3_scale(float* __restrict__ out,
                                                const float* __restrict__ colnorm) {
  int b = blockIdx.x;  // 1152
  int reg = b % 288;   // match k2's writer XCD for L2 reuse
  int dc = b / 288;

  __shared__ float ratio[64];
  __shared__ float fs[64];
  int t = threadIdx.x;
  float c = 0.f;
  if (t < 64) {
#pragma unroll
    for (int j = 0; j < 8; ++j) c += colnorm[(size_t)(reg * 8 + j) * 64 + t];
    ratio[t] = c / (c + EPSF);
  }
  __syncthreads();
  if (t < 64) {
    float g = 0.f;
#pragma unroll
    for (int j = 0; j < 64; ++j) g += ratio[j];
    fs[t] = rsqrtf(c + EPSF) * rsqrtf(g + EPSF);
  }
  __syncthreads();

  size_t base4 = (((size_t)reg * 512) + (size_t)dc * 128) * 64 / 4;
  float4* o4 = reinterpret_cast<float4*>(out);
  for (int j = 0; j < 8; ++j) {
    size_t idx = base4 + t + 256 * j;
    float4 v = o4[idx];
    int k0 = (int)((idx * 4) & 63);
    v.x *= fs[k0]; v.y *= fs[k0 + 1]; v.z *= fs[k0 + 2]; v.w *= fs[k0 + 3];
    o4[idx] = v;
  }
}

extern "C" void kernel_launch(void* const* d_in, const int* in_sizes, int n_in,
                              void* d_out, int out_size, void* d_ws, size_t ws_size,
                              hipStream_t stream) {
  const float* x = (const float*)d_in[0];   // [32,36,36,512]
  const float* Wc = (const float*)d_in[1];  // [512,64]
  const float* C = (const float*)d_in[2];   // [512,64]
  float* out = (float*)d_out;

  char* ws = (char*)d_ws;
  ushort* ws2 = (ushort*)(ws);              // 131072 B (2 x 64KB planes)
  float* asum_ws = (float*)(ws + 131072);   // 864*64*4 = 221184 B
  float* colnorm = (float*)(ws + 352256);   // 2304*64*4 = 589824 B
  float4* aT_ws = (float4*)(ws + 942080);   // 288 * 38912 B = 11.2 MB

  k0_wt<<<64, 256, 0, stream>>>(Wc, ws2);
  k1_assign<<<864, 512, 0, stream>>>(x, ws2, aT_ws, asum_ws);
  k2_vlad<<<2304, 512, 0, stream>>>(x, C, aT_ws, asum_ws, out, colnorm);
  k3_scale<<<1152, 256, 0, stream>>>(out, colnorm);
}